// Round 1
// baseline (1679.771 us; speedup 1.0000x reference)
//
#include <hip/hip_runtime.h>

typedef _Float16 half8 __attribute__((ext_vector_type(8)));
typedef float f32x4 __attribute__((ext_vector_type(4)));

#define B_SZ   2048
#define T_SZ   128
#define IN_SZ  64
#define H_SZ   256
#define G4     1024          // 4*H
#define KTOT   320           // IN + H
#define KT_N   10            // K tiles of 32
#define M_BLK  16
#define NBLK   (B_SZ / M_BLK)   // 128 blocks
#define NTHR   512              // 8 waves
#define A_PAD  328              // LDS A row stride in halves (656B = 41*16, bank-uniform)

__device__ __forceinline__ float sigmoidf_(float x) {
  return 1.0f / (1.0f + __expf(-x));
}
__device__ __forceinline__ float tanhf_(float x) {
  // exact identity tanh(x) = 1 - 2/(e^{2x}+1); robust at +-inf
  return 1.0f - 2.0f / (__expf(2.0f * x) + 1.0f);
}

// Repack [W_ih | W_hh] -> fp16, gate-reordered, MFMA-fragment-ordered.
// New row index rp = w*128 + q*32 + j  (w=wave 0..7, q=gate i/f/g/o, j=hcol%32)
// maps to original gate row g = q*256 + w*32 + j.
// Storage: tile (nb,kt) = 16 cols x 32 k, flat [(nb*10+kt)*64 + lane]*8 halves,
// lane l holds row nb*16+(l&15), k = kt*32 + (l>>4)*8 .. +8  (A/B frag layout).
__global__ void prep_kernel(const float* __restrict__ W_ih,
                            const float* __restrict__ W_hh,
                            const float* __restrict__ b_ih,
                            const float* __restrict__ b_hh,
                            _Float16* __restrict__ Wpp,
                            float* __restrict__ biasp) {
  const int tid = blockIdx.x * blockDim.x + threadIdx.x;  // 0..40959
  if (tid < G4) {
    const int rp = tid;
    const int w = rp >> 7, q = (rp >> 5) & 3, j = rp & 31;
    const int g = q * 256 + w * 32 + j;
    biasp[rp] = b_ih[g] + b_hh[g];
  }
  const int l  = tid & 63;
  const int kt = (tid >> 6) % KT_N;
  const int nb = tid / (64 * KT_N);
  if (nb >= G4 / 16) return;
  const int rp = nb * 16 + (l & 15);
  const int w = rp >> 7, q = (rp >> 5) & 3, j = rp & 31;
  const int g = q * 256 + w * 32 + j;
  const int k0 = kt * 32 + (l >> 4) * 8;
  _Float16 v[8];
  #pragma unroll
  for (int kk = 0; kk < 8; ++kk) {
    const int k = k0 + kk;
    const float f = (k < IN_SZ) ? W_ih[g * IN_SZ + k]
                                : W_hh[g * H_SZ + (k - IN_SZ)];
    v[kk] = (_Float16)f;
  }
  *(half8*)(Wpp + ((size_t)(nb * KT_N + kt) * 64 + l) * 8) = *(half8*)v;
}

__global__ __launch_bounds__(NTHR, 2)
void lstm_kernel(const float* __restrict__ x,
                 const _Float16* __restrict__ Wpp,
                 const float* __restrict__ biasp,
                 const float* __restrict__ fcW,
                 const float* __restrict__ fcb,
                 float* __restrict__ out) {
  __shared__ __align__(16) _Float16 Abuf[M_BLK][A_PAD];  // [x_t | h] fp16
  __shared__ float hbuf[M_BLK][H_SZ];                    // final h, f32
  __shared__ float red[M_BLK][16];

  const int tid = threadIdx.x;
  const int l   = tid & 63;
  const int w   = tid >> 6;     // wave 0..7 -> owns h-cols [w*32, w*32+32)
  const int lm  = l & 15;
  const int lk  = l >> 4;
  const int r0  = blockIdx.x * M_BLK;

  float bias[8];
  #pragma unroll
  for (int nt = 0; nt < 8; ++nt) bias[nt] = biasp[w * 128 + nt * 16 + lm];

  // stage x_0, zero h region
  {
    const int r = tid >> 5;
    const int i2 = (tid & 31) * 2;
    const float* xp = x + ((size_t)(r0 + r) * T_SZ) * IN_SZ + i2;
    Abuf[r][i2]     = (_Float16)xp[0];
    Abuf[r][i2 + 1] = (_Float16)xp[1];
  }
  #pragma unroll
  for (int z = 0; z < 8; ++z) {
    const int idx = tid * 8 + z;              // 0..4095 = 16*256
    Abuf[idx >> 8][IN_SZ + (idx & 255)] = (_Float16)0.0f;
  }
  __syncthreads();

  float c[2][4] = {};   // cell state: [jhalf][row], h-col = w*32+jh*16+lm, row = lk*4+r
  const _Float16* wbase = Wpp + (size_t)w * 8 * KT_N * 512 + (size_t)l * 8;

  for (int t = 0; t < T_SZ; ++t) {
    // A fragments for this step (all waves read same 16x320 tile)
    half8 afr[KT_N];
    #pragma unroll
    for (int kt = 0; kt < KT_N; ++kt)
      afr[kt] = *(const half8*)&Abuf[lm][kt * 32 + lk * 8];
    __syncthreads();  // all reads done; LDS writable

    // stage x_{t+1} (overlaps with GEMM below)
    if (t + 1 < T_SZ) {
      const int r = tid >> 5;
      const int i2 = (tid & 31) * 2;
      const float* xp = x + ((size_t)(r0 + r) * T_SZ + (t + 1)) * IN_SZ + i2;
      Abuf[r][i2]     = (_Float16)xp[0];
      Abuf[r][i2 + 1] = (_Float16)xp[1];
    }

    // gates[16 rows][128 cols of this wave] = A @ W'^T  (W'' streamed from L2)
    f32x4 acc[8] = {};
    #pragma unroll
    for (int kt = 0; kt < KT_N; ++kt) {
      #pragma unroll
      for (int nt = 0; nt < 8; ++nt) {
        const half8 bfr = *(const half8*)(wbase + (size_t)(nt * KT_N + kt) * 512);
        acc[nt] = __builtin_amdgcn_mfma_f32_16x16x32_f16(afr[kt], bfr, acc[nt], 0, 0, 0);
      }
    }

    // cell update: acc tile nt = q*2 + jh holds gate q, h-col w*32 + jh*16 + lm
    #pragma unroll
    for (int jh = 0; jh < 2; ++jh) {
      #pragma unroll
      for (int r = 0; r < 4; ++r) {
        const float iv = sigmoidf_(acc[0 + jh][r] + bias[0 + jh]);
        const float fv = sigmoidf_(acc[2 + jh][r] + bias[2 + jh]);
        const float gv = tanhf_   (acc[4 + jh][r] + bias[4 + jh]);
        const float ov = sigmoidf_(acc[6 + jh][r] + bias[6 + jh]);
        const float cn = fv * c[jh][r] + iv * gv;
        c[jh][r] = cn;
        const float hv = ov * tanhf_(cn);
        const int m   = lk * 4 + r;
        const int col = w * 32 + jh * 16 + lm;
        Abuf[m][IN_SZ + col] = (_Float16)hv;      // h for next step (fp16)
        if (t == T_SZ - 1) hbuf[m][col] = hv;     // final h (f32)
      }
    }
    __syncthreads();  // h/x writes visible for next step
  }

  // out[r] = h_last[r,:] . fcW + fcb
  if (tid < 256) {
    const int r = tid >> 4, c0 = tid & 15;
    float p = 0.f;
    #pragma unroll
    for (int cc = 0; cc < 16; ++cc)
      p += hbuf[r][c0 + cc * 16] * fcW[c0 + cc * 16];
    red[r][c0] = p;
  }
  __syncthreads();
  if (tid < M_BLK) {
    float s = 0.f;
    #pragma unroll
    for (int k = 0; k < 16; ++k) s += red[tid][k];
    out[r0 + tid] = s + fcb[0];
  }
}

extern "C" void kernel_launch(void* const* d_in, const int* in_sizes, int n_in,
                              void* d_out, int out_size, void* d_ws, size_t ws_size,
                              hipStream_t stream) {
  const float* x    = (const float*)d_in[0];
  const float* W_ih = (const float*)d_in[1];
  const float* W_hh = (const float*)d_in[2];
  const float* b_ih = (const float*)d_in[3];
  const float* b_hh = (const float*)d_in[4];
  const float* fcW  = (const float*)d_in[5];
  const float* fcb  = (const float*)d_in[6];
  float* out = (float*)d_out;

  // ws layout: W'' fp16 [1024*320] = 655360 B, then bias' f32 [1024] = 4096 B
  _Float16* Wpp = (_Float16*)d_ws;
  float* biasp  = (float*)((char*)d_ws + (size_t)G4 * KTOT * sizeof(_Float16));

  hipLaunchKernelGGL(prep_kernel, dim3(160), dim3(256), 0, stream,
                     W_ih, W_hh, b_ih, b_hh, Wpp, biasp);
  hipLaunchKernelGGL(lstm_kernel, dim3(NBLK), dim3(NTHR), 0, stream,
                     x, Wpp, biasp, fcW, fcb, out);
}

// Round 2
// 1152.799 us; speedup vs baseline: 1.4571x; 1.4571x over previous
//
#include <hip/hip_runtime.h>

typedef _Float16 half8 __attribute__((ext_vector_type(8)));
typedef float f32x4 __attribute__((ext_vector_type(4)));

#define B_SZ   2048
#define T_SZ   128
#define IN_SZ  64
#define H_SZ   256
#define G4     1024          // 4*H
#define KTOT   320           // IN + H
#define KT_N   10            // K tiles of 32
#define M_BLK  8
#define NBLK   (B_SZ / M_BLK)   // 256 blocks -> 1 per CU
#define NTHR   512              // 8 waves
#define A_PAD  328              // LDS A row stride in halves (656B = 41*16, bank-uniform)
#define KT_REG 3                // kt 0..2 resident in VGPRs (24 frags/wave, 96 VGPR)
#define KT_LDS 2                // kt 3..4 resident in LDS (16 frags/wave, 128 KB/block)

__device__ __forceinline__ float sigmoidf_(float x) {
  return 1.0f / (1.0f + __expf(-x));
}
__device__ __forceinline__ float tanhf_(float x) {
  return 1.0f - 2.0f / (__expf(2.0f * x) + 1.0f);
}

// Repack [W_ih | W_hh] -> fp16, gate-reordered, MFMA-fragment-ordered.
// rp = w*128 + q*32 + j  ->  original gate row g = q*256 + w*32 + j.
// Frag (nb,kt): flat [(nb*10+kt)*64 + lane]*8 halves; lane l holds row
// nb*16+(l&15), k = kt*32 + (l>>4)*8 .. +8.
__global__ void prep_kernel(const float* __restrict__ W_ih,
                            const float* __restrict__ W_hh,
                            const float* __restrict__ b_ih,
                            const float* __restrict__ b_hh,
                            _Float16* __restrict__ Wpp,
                            float* __restrict__ biasp) {
  const int tid = blockIdx.x * blockDim.x + threadIdx.x;
  if (tid < G4) {
    const int rp = tid;
    const int w = rp >> 7, q = (rp >> 5) & 3, j = rp & 31;
    const int g = q * 256 + w * 32 + j;
    biasp[rp] = b_ih[g] + b_hh[g];
  }
  const int l  = tid & 63;
  const int kt = (tid >> 6) % KT_N;
  const int nb = tid / (64 * KT_N);
  if (nb >= G4 / 16) return;
  const int rp = nb * 16 + (l & 15);
  const int w = rp >> 7, q = (rp >> 5) & 3, j = rp & 31;
  const int g = q * 256 + w * 32 + j;
  const int k0 = kt * 32 + (l >> 4) * 8;
  _Float16 v[8];
  #pragma unroll
  for (int kk = 0; kk < 8; ++kk) {
    const int k = k0 + kk;
    const float f = (k < IN_SZ) ? W_ih[g * IN_SZ + k]
                                : W_hh[g * H_SZ + (k - IN_SZ)];
    v[kk] = (_Float16)f;
  }
  *(half8*)(Wpp + ((size_t)(nb * KT_N + kt) * 64 + l) * 8) = *(half8*)v;
}

__global__ __launch_bounds__(NTHR, 2)
void lstm_kernel(const float* __restrict__ x,
                 const _Float16* __restrict__ Wpp,
                 const float* __restrict__ biasp,
                 const float* __restrict__ fcW,
                 const float* __restrict__ fcb,
                 float* __restrict__ out) {
  // LDS: A double-buffered (rows 8..15 stay zero), B kt3..4 resident, FC scratch
  __shared__ __align__(16) _Float16 Abuf[2][16][A_PAD];   // 20992 B
  __shared__ __align__(16) _Float16 Blds[128 * 512];      // 131072 B
  __shared__ float red[M_BLK][16];                        // 512 B

  const int tid = threadIdx.x;
  const int l   = tid & 63;
  const int w   = tid >> 6;     // wave 0..7 -> owns h-cols [w*32, w*32+32)
  const int lm  = l & 15;
  const int lk  = l >> 4;
  const int r0  = blockIdx.x * M_BLK;

  // zero Abuf entirely (h_{-1}=0; rows 8..15 permanently zero)
  {
    _Float16* ab = &Abuf[0][0][0];
    for (int i = tid; i < 2 * 16 * A_PAD; i += NTHR) ab[i] = (_Float16)0.0f;
  }

  float bias[8];
  #pragma unroll
  for (int nt = 0; nt < 8; ++nt) bias[nt] = biasp[w * 128 + nt * 16 + lm];

  const _Float16* wbase = Wpp + (size_t)w * 8 * KT_N * 512 + (size_t)l * 8;

  // register-resident B: kt 0..2
  half8 bres[8][KT_REG];
  #pragma unroll
  for (int nt = 0; nt < 8; ++nt) {
    #pragma unroll
    for (int kt = 0; kt < KT_REG; ++kt)
      bres[nt][kt] = *(const half8*)(wbase + (size_t)(nt * KT_N + kt) * 512);
  }

  __syncthreads();  // zeroing visible before x_0 / h writes

  // stage x_0 into buf 0
  {
    const int r = tid >> 6, cc = tid & 63;
    Abuf[0][r][cc] = (_Float16)x[((size_t)(r0 + r) * T_SZ) * IN_SZ + cc];
  }
  // LDS-resident B: kt 3..4
  #pragma unroll
  for (int nt = 0; nt < 8; ++nt) {
    #pragma unroll
    for (int j = 0; j < KT_LDS; ++j)
      *(half8*)&Blds[((w * 16 + nt * 2 + j) * 512) + l * 8] =
          *(const half8*)(wbase + (size_t)(nt * KT_N + KT_REG + j) * 512);
  }

  __syncthreads();

  float cst[2][4] = {};   // cell state (valid on lanes lk<2)

  for (int t = 0; t < T_SZ; ++t) {
    const _Float16 (*Ain)[A_PAD] = Abuf[t & 1];
    _Float16 (*Aout)[A_PAD] = Abuf[(t + 1) & 1];

    // streamed B: issue kt5, kt6 loads up front (consumed after resident MFMAs)
    half8 sA[8], sB[8];
    #pragma unroll
    for (int nt = 0; nt < 8; ++nt)
      sA[nt] = *(const half8*)(wbase + (size_t)(nt * KT_N + 5) * 512);
    #pragma unroll
    for (int nt = 0; nt < 8; ++nt)
      sB[nt] = *(const half8*)(wbase + (size_t)(nt * KT_N + 6) * 512);

    // stage x_{t+1} into the other buffer (overlaps GEMM)
    if (t + 1 < T_SZ) {
      const int r = tid >> 6, cc = tid & 63;
      Aout[r][cc] = (_Float16)x[((size_t)(r0 + r) * T_SZ + (t + 1)) * IN_SZ + cc];
    }

    #define LA(kt) (*(const half8*)&Ain[lm][(kt) * 32 + lk * 8])
    half8 a_cur = LA(0), a_n1 = LA(1), a_n2 = LA(2);

    f32x4 acc[8];
    #pragma unroll
    for (int nt = 0; nt < 8; ++nt) acc[nt] = (f32x4){0.f, 0.f, 0.f, 0.f};

    // kt 0..2: register-resident B
    #pragma unroll
    for (int nt = 0; nt < 8; ++nt)
      acc[nt] = __builtin_amdgcn_mfma_f32_16x16x32_f16(a_cur, bres[nt][0], acc[nt], 0, 0, 0);
    a_cur = a_n1; a_n1 = a_n2; a_n2 = LA(3);
    #pragma unroll
    for (int nt = 0; nt < 8; ++nt)
      acc[nt] = __builtin_amdgcn_mfma_f32_16x16x32_f16(a_cur, bres[nt][1], acc[nt], 0, 0, 0);
    a_cur = a_n1; a_n1 = a_n2; a_n2 = LA(4);
    #pragma unroll
    for (int nt = 0; nt < 8; ++nt)
      acc[nt] = __builtin_amdgcn_mfma_f32_16x16x32_f16(a_cur, bres[nt][2], acc[nt], 0, 0, 0);
    a_cur = a_n1; a_n1 = a_n2; a_n2 = LA(5);

    // kt 3..4: LDS-resident B
    #pragma unroll
    for (int nt = 0; nt < 8; ++nt) {
      const half8 bl = *(const half8*)&Blds[((w * 16 + nt * 2 + 0) * 512) + l * 8];
      acc[nt] = __builtin_amdgcn_mfma_f32_16x16x32_f16(a_cur, bl, acc[nt], 0, 0, 0);
    }
    a_cur = a_n1; a_n1 = a_n2; a_n2 = LA(6);
    #pragma unroll
    for (int nt = 0; nt < 8; ++nt) {
      const half8 bl = *(const half8*)&Blds[((w * 16 + nt * 2 + 1) * 512) + l * 8];
      acc[nt] = __builtin_amdgcn_mfma_f32_16x16x32_f16(a_cur, bl, acc[nt], 0, 0, 0);
    }
    a_cur = a_n1; a_n1 = a_n2; a_n2 = LA(7);

    // kt 5..9: streamed B, ping-pong
    #pragma unroll
    for (int nt = 0; nt < 8; ++nt)
      acc[nt] = __builtin_amdgcn_mfma_f32_16x16x32_f16(a_cur, sA[nt], acc[nt], 0, 0, 0);
    #pragma unroll
    for (int nt = 0; nt < 8; ++nt)
      sA[nt] = *(const half8*)(wbase + (size_t)(nt * KT_N + 7) * 512);
    a_cur = a_n1; a_n1 = a_n2; a_n2 = LA(8);

    #pragma unroll
    for (int nt = 0; nt < 8; ++nt)
      acc[nt] = __builtin_amdgcn_mfma_f32_16x16x32_f16(a_cur, sB[nt], acc[nt], 0, 0, 0);
    #pragma unroll
    for (int nt = 0; nt < 8; ++nt)
      sB[nt] = *(const half8*)(wbase + (size_t)(nt * KT_N + 8) * 512);
    a_cur = a_n1; a_n1 = a_n2; a_n2 = LA(9);

    #pragma unroll
    for (int nt = 0; nt < 8; ++nt)
      acc[nt] = __builtin_amdgcn_mfma_f32_16x16x32_f16(a_cur, sA[nt], acc[nt], 0, 0, 0);
    #pragma unroll
    for (int nt = 0; nt < 8; ++nt)
      sA[nt] = *(const half8*)(wbase + (size_t)(nt * KT_N + 9) * 512);
    a_cur = a_n1; a_n1 = a_n2;

    #pragma unroll
    for (int nt = 0; nt < 8; ++nt)
      acc[nt] = __builtin_amdgcn_mfma_f32_16x16x32_f16(a_cur, sB[nt], acc[nt], 0, 0, 0);
    a_cur = a_n1;

    #pragma unroll
    for (int nt = 0; nt < 8; ++nt)
      acc[nt] = __builtin_amdgcn_mfma_f32_16x16x32_f16(a_cur, sA[nt], acc[nt], 0, 0, 0);
    #undef LA

    // cell update: acc tile nt = q*2 + jh; h-col = w*32 + jh*16 + lm; rows lk*4+r (valid lk<2)
    #pragma unroll
    for (int jh = 0; jh < 2; ++jh) {
      #pragma unroll
      for (int r = 0; r < 4; ++r) {
        const float iv = sigmoidf_(acc[0 + jh][r] + bias[0 + jh]);
        const float fv = sigmoidf_(acc[2 + jh][r] + bias[2 + jh]);
        const float gv = tanhf_   (acc[4 + jh][r] + bias[4 + jh]);
        const float ov = sigmoidf_(acc[6 + jh][r] + bias[6 + jh]);
        const float cn = fv * cst[jh][r] + iv * gv;
        cst[jh][r] = cn;
        const float hv = ov * tanhf_(cn);
        if (lk < 2) {
          const int m   = lk * 4 + r;
          const int col = w * 32 + jh * 16 + lm;
          Aout[m][IN_SZ + col] = (_Float16)hv;
        }
      }
    }
    __syncthreads();  // step-t reads done AND h/x writes visible
  }

  // out[r] = h_last[r,:] . fcW + fcb  (h_last is in Abuf[0] h-region, fp16)
  if (tid < 128) {
    const int r = tid >> 4, c0 = tid & 15;
    float p = 0.f;
    #pragma unroll
    for (int cc = 0; cc < 16; ++cc) {
      const int col = c0 + cc * 16;
      p += (float)Abuf[0][r][IN_SZ + col] * fcW[col];
    }
    red[r][c0] = p;
  }
  __syncthreads();
  if (tid < M_BLK) {
    float s = 0.f;
    #pragma unroll
    for (int k = 0; k < 16; ++k) s += red[tid][k];
    out[r0 + tid] = s + fcb[0];
  }
}

extern "C" void kernel_launch(void* const* d_in, const int* in_sizes, int n_in,
                              void* d_out, int out_size, void* d_ws, size_t ws_size,
                              hipStream_t stream) {
  const float* x    = (const float*)d_in[0];
  const float* W_ih = (const float*)d_in[1];
  const float* W_hh = (const float*)d_in[2];
  const float* b_ih = (const float*)d_in[3];
  const float* b_hh = (const float*)d_in[4];
  const float* fcW  = (const float*)d_in[5];
  const float* fcb  = (const float*)d_in[6];
  float* out = (float*)d_out;

  _Float16* Wpp = (_Float16*)d_ws;
  float* biasp  = (float*)((char*)d_ws + (size_t)G4 * KTOT * sizeof(_Float16));

  hipLaunchKernelGGL(prep_kernel, dim3(160), dim3(256), 0, stream,
                     W_ih, W_hh, b_ih, b_hh, Wpp, biasp);
  hipLaunchKernelGGL(lstm_kernel, dim3(NBLK), dim3(NTHR), 0, stream,
                     x, Wpp, biasp, fcW, fcb, out);
}